// Round 15
// baseline (138.867 us; speedup 1.0000x reference)
//
#include <hip/hip_runtime.h>
#include <hip/hip_bf16.h>

#define FLOAT_EPS 1.1920928955078125e-07f

typedef float f32x4 __attribute__((ext_vector_type(4)));
typedef short s16x8 __attribute__((ext_vector_type(8)));
typedef unsigned int u32x2 __attribute__((ext_vector_type(2)));

#define B_ 16
#define P_ 8192
#define I_ 256
#define O_ 128
#define L_ 256
#define IO_ (I_*O_)   // 32768

__device__ __forceinline__ float clip01(float v) {
    return fminf(fmaxf(v, 0.0f), 1.0f);
}
__device__ __forceinline__ f32x4 clip01v(f32x4 v) {
    f32x4 r;
    r[0] = clip01(v[0]); r[1] = clip01(v[1]);
    r[2] = clip01(v[2]); r[3] = clip01(v[3]);
    return r;
}

// ---------------- K1: partial logits, l split 2-way; lat read via scalar loads ------
// grid (128, 2, 2) = (n-block, ks, l-half), block 256.
__global__ __launch_bounds__(256) void rl_k1_logits(
        const float* __restrict__ lat,
        const float* __restrict__ c1, const float* __restrict__ c2,
        float* __restrict__ lgP) {
    const int n  = blockIdx.x * 256 + threadIdx.x;
    const int ks = blockIdx.y;
    const int lh = blockIdx.z;
    const float* __restrict__ C  = (ks ? c2 : c1) + (size_t)lh * 128 * IO_;
    const int lbase = lh * 128;

    float acc[16];
#pragma unroll
    for (int b = 0; b < 16; ++b) acc[b] = 0.0f;

#pragma unroll 4
    for (int l = 0; l < 128; ++l) {
        float cv = C[(size_t)l * IO_ + n];
#pragma unroll
        for (int b = 0; b < 16; ++b)
            acc[b] += lat[b * L_ + lbase + l] * cv;   // uniform -> s_load
    }
    float* o = lgP + ((size_t)(lh * 32 + ks * 16)) * IO_ + n;
#pragma unroll
    for (int b = 0; b < 16; ++b) o[(size_t)b * IO_] = acc[b];
}

// ---------------- K2: double softmax over i, write mask fragment-major bf16 ---------
// grid (8, 2, 16) = (o-tile16, ks, b), block 256 = 16 i-groups x 16 o-lanes.
// k-slot mapping (shared with K3): slot (kk,lhi,e) <-> global k = kk*32 + (e>>2)*16
// + lhi*4 + (e&3). Chunk j = (f*8+kk)*64 + lhi*16 + l15 holds the 8 bf16 slots of
// fragment row n = f*16+l15. Thread g = kk*2+h owns i-range kk*32+h*16..+16 and
// writes the e = h*4..h*4+3 half (8 B) of the 4 lhi-chunks.
__global__ __launch_bounds__(256) void rl_k2_mask(
        const float* __restrict__ lgP, const float* __restrict__ u,
        const float* __restrict__ temp_p, __hip_bfloat16* __restrict__ MTF) {
    const int oo = threadIdx.x & 15;
    const int g  = threadIdx.x >> 4;     // 16 groups, 16 i's each
    const int o0 = blockIdx.x * 16;
    const int ks = blockIdx.y;
    const int b  = blockIdx.z;

    __shared__ float slab[I_][16];
    __shared__ float red[16][16];

    const float* __restrict__ z0 = lgP + (size_t)(ks * 16 + b) * IO_ + o0 + oo;
    const float* __restrict__ z1 = z0 + (size_t)32 * IO_;
    const float* __restrict__ up = u + ((size_t)b * 2 + ks) * IO_ + o0 + oo;

    float T = temp_p[0];
    T = fminf(fmaxf(T, FLOAT_EPS), 2.0f);
    T = fmaxf(T, 0.001f);
    const float rT = 1.0f / T;

    const int i0 = g * 16, i1 = i0 + 16;

    for (int i = i0; i < i1; ++i)
        slab[i][oo] = z0[(size_t)i * O_] + z1[(size_t)i * O_];
    __syncthreads();

    float m = -INFINITY;
    for (int i = i0; i < i1; ++i) m = fmaxf(m, slab[i][oo]);
    red[g][oo] = m; __syncthreads();
    m = -INFINITY;
#pragma unroll
    for (int j = 0; j < 16; ++j) m = fmaxf(m, red[j][oo]);
    __syncthreads();

    float S = 0.0f;
    for (int i = i0; i < i1; ++i) S += expf(slab[i][oo] - m);
    red[g][oo] = S; __syncthreads();
    S = 0.0f;
#pragma unroll
    for (int j = 0; j < 16; ++j) S += red[j][oo];
    __syncthreads();
    const float invS = 1.0f / S;

    float m2 = -INFINITY;
    for (int i = i0; i < i1; ++i) {
        float p  = expf(slab[i][oo] - m) * invS;
        float uu = fmaxf(up[(size_t)i * O_], FLOAT_EPS);
        float gg = -logf(-logf(uu));
        float s  = (logf(p + FLOAT_EPS) + gg) * rT;
        slab[i][oo] = s;
        m2 = fmaxf(m2, s);
    }
    red[g][oo] = m2; __syncthreads();
    m2 = -INFINITY;
#pragma unroll
    for (int j = 0; j < 16; ++j) m2 = fmaxf(m2, red[j][oo]);
    __syncthreads();

    float S2 = 0.0f;
    for (int i = i0; i < i1; ++i) S2 += expf(slab[i][oo] - m2);
    red[g][oo] = S2; __syncthreads();
    S2 = 0.0f;
#pragma unroll
    for (int j = 0; j < 16; ++j) S2 += red[j][oo];
    const float invS2 = 1.0f / S2;

    // pass 5: fragment-major write in kappa-order. n = ks*128+o0+oo (l15 = oo).
    const int n  = ks * 128 + o0 + oo;
    const int f  = n >> 4;
    const int kk = g >> 1, h = g & 1;
    char* mb = (char*)((s16x8*)MTF + (size_t)b * 8192);

#pragma unroll
    for (int lh = 0; lh < 4; ++lh) {
        const int j = (f * 8 + kk) * 64 + lh * 16 + oo;
        float v0 = expf(slab[i0 + lh * 4 + 0][oo] - m2) * invS2;
        float v1 = expf(slab[i0 + lh * 4 + 1][oo] - m2) * invS2;
        float v2 = expf(slab[i0 + lh * 4 + 2][oo] - m2) * invS2;
        float v3 = expf(slab[i0 + lh * 4 + 3][oo] - m2) * invS2;
        union { u32x2 u; __hip_bfloat162 h2[2]; } pk;
        pk.h2[0] = __float22bfloat162_rn(make_float2(v0, v1));
        pk.h2[1] = __float22bfloat162_rn(make_float2(v2, v3));
        *(u32x2*)(mb + (size_t)j * 16 + h * 8) = pk.u;
    }
}

// ---------------- K3: fragment-major LDS B, 16 waves, FULL-LINE x loads -------------
// grid (16, 16) = (512-row slab, b), block 1024 = 16 waves, 32 rows/wave (2 chunks).
// k-slot kappa mapping: x float4 #1 reads floats kk*32 + lhi*4 (16-B lane stride ->
// each 64-B request fully utilized), #2 reads +16. Mask chunks written by K2 in the
// same kappa order, so mfma contraction is unchanged.
// B fragments lane-contiguous in LDS: read = base + lane*16 -> zero bank conflicts.
// mfma(A=mask, B=x) -> D[n][p]: lane col (l15) = output row p, regs = 4 consecutive n.
__global__ __launch_bounds__(1024, 4) void rl_k3_gemm(
        const float* __restrict__ X, const __hip_bfloat16* __restrict__ MTF,
        float* __restrict__ OUT) {
    const int tid  = threadIdx.x;
    const int lane = tid & 63, wid = tid >> 6;   // 16 waves
    const int b    = blockIdx.y;

    __shared__ s16x8 BF[8192];   // 128 KB, fragment-major (identity copy of MTF[b])

    const float* __restrict__ Xb    = X + (size_t)b * P_ * I_;
    const s16x8* __restrict__ MTFb  = (const s16x8*)MTF + (size_t)b * 8192;
    float* __restrict__ Ob          = OUT + (size_t)b * P_ * 512;

    const int l15 = lane & 15, lhi = lane >> 4;
    const int lhi4 = lhi * 4;
    const int rowbase = blockIdx.x * 512 + wid * 32 + l15;

    // issue x chunk-0 loads first (latency hides under B staging + barrier)
    float4 raw[16];
    const float* s0 = Xb + (size_t)rowbase * I_ + lhi4;
#pragma unroll
    for (int kk = 0; kk < 8; ++kk) {
        raw[2 * kk]     = *(const float4*)(s0 + kk * 32);
        raw[2 * kk + 1] = *(const float4*)(s0 + kk * 32 + 16);
    }

    // stage B: identity copy, coalesced global reads, conflict-free LDS writes
#pragma unroll
    for (int it = 0; it < 8; ++it) {
        int j = it * 1024 + tid;
        BF[j] = MTFb[j];
    }
    __syncthreads();

    const float* s1 = Xb + (size_t)(rowbase + 16) * I_ + lhi4;

    // ---- chunk 0: compute with chunk-1 prefetch spread through the fn loop ----
    {
        s16x8 af[8];
#pragma unroll
        for (int kk = 0; kk < 8; ++kk) {
            float4 f0 = raw[2 * kk], f1 = raw[2 * kk + 1];
            union { s16x8 v; __hip_bfloat162 h[4]; } cv;
            cv.h[0] = __float22bfloat162_rn(make_float2(f0.x, f0.y));
            cv.h[1] = __float22bfloat162_rn(make_float2(f0.z, f0.w));
            cv.h[2] = __float22bfloat162_rn(make_float2(f1.x, f1.y));
            cv.h[3] = __float22bfloat162_rn(make_float2(f1.z, f1.w));
            af[kk] = cv.v;
        }
        const int prow = blockIdx.x * 512 + wid * 32 + l15;
        float* __restrict__ oprow = Ob + (size_t)prow * 512 + lhi4;

#pragma unroll
        for (int fn = 0; fn < 8; ++fn) {
            // 2 of chunk-1's 16 loads, pinned here -> continuous read issue
            raw[2 * fn]     = *(const float4*)(s1 + fn * 32);
            raw[2 * fn + 1] = *(const float4*)(s1 + fn * 32 + 16);
            __builtin_amdgcn_sched_barrier(0);

            f32x4 acc_a = (f32x4){0.f, 0.f, 0.f, 0.f};
            f32x4 acc_b = (f32x4){0.f, 0.f, 0.f, 0.f};
            const s16x8* pA = BF + (fn * 8) * 64 + lane;
            const s16x8* pB = BF + ((fn + 8) * 8) * 64 + lane;
#pragma unroll
            for (int kk = 0; kk < 8; ++kk) {
                s16x8 bfa = pA[kk * 64];
                s16x8 bfb = pB[kk * 64];
                acc_a = __builtin_amdgcn_mfma_f32_16x16x32_bf16(bfa, af[kk], acc_a, 0, 0, 0);
                acc_b = __builtin_amdgcn_mfma_f32_16x16x32_bf16(bfb, af[kk], acc_b, 0, 0, 0);
            }
            f32x4 s = acc_a + acc_b;
            float* op = oprow + fn * 16;
            __builtin_nontemporal_store(clip01v(s),             (f32x4*)(op));
            __builtin_nontemporal_store(clip01v(s - 1.0f),      (f32x4*)(op + 128));
            __builtin_nontemporal_store(clip01v(acc_a - acc_b), (f32x4*)(op + 256));
            __builtin_nontemporal_store(clip01v(acc_b - acc_a), (f32x4*)(op + 384));
            __builtin_amdgcn_sched_barrier(0);
        }
    }

    // ---- chunk 1: plain compute (no further prefetch) ----
    {
        s16x8 af[8];
#pragma unroll
        for (int kk = 0; kk < 8; ++kk) {
            float4 f0 = raw[2 * kk], f1 = raw[2 * kk + 1];
            union { s16x8 v; __hip_bfloat162 h[4]; } cv;
            cv.h[0] = __float22bfloat162_rn(make_float2(f0.x, f0.y));
            cv.h[1] = __float22bfloat162_rn(make_float2(f0.z, f0.w));
            cv.h[2] = __float22bfloat162_rn(make_float2(f1.x, f1.y));
            cv.h[3] = __float22bfloat162_rn(make_float2(f1.z, f1.w));
            af[kk] = cv.v;
        }
        const int prow = blockIdx.x * 512 + wid * 32 + 16 + l15;
        float* __restrict__ oprow = Ob + (size_t)prow * 512 + lhi4;

#pragma unroll
        for (int fn = 0; fn < 8; ++fn) {
            f32x4 acc_a = (f32x4){0.f, 0.f, 0.f, 0.f};
            f32x4 acc_b = (f32x4){0.f, 0.f, 0.f, 0.f};
            const s16x8* pA = BF + (fn * 8) * 64 + lane;
            const s16x8* pB = BF + ((fn + 8) * 8) * 64 + lane;
#pragma unroll
            for (int kk = 0; kk < 8; ++kk) {
                s16x8 bfa = pA[kk * 64];
                s16x8 bfb = pB[kk * 64];
                acc_a = __builtin_amdgcn_mfma_f32_16x16x32_bf16(bfa, af[kk], acc_a, 0, 0, 0);
                acc_b = __builtin_amdgcn_mfma_f32_16x16x32_bf16(bfb, af[kk], acc_b, 0, 0, 0);
            }
            f32x4 s = acc_a + acc_b;
            float* op = oprow + fn * 16;
            __builtin_nontemporal_store(clip01v(s),             (f32x4*)(op));
            __builtin_nontemporal_store(clip01v(s - 1.0f),      (f32x4*)(op + 128));
            __builtin_nontemporal_store(clip01v(acc_a - acc_b), (f32x4*)(op + 256));
            __builtin_nontemporal_store(clip01v(acc_b - acc_a), (f32x4*)(op + 384));
        }
    }
}

extern "C" void kernel_launch(void* const* d_in, const int* in_sizes, int n_in,
                              void* d_out, int out_size, void* d_ws, size_t ws_size,
                              hipStream_t stream) {
    const float* x    = (const float*)d_in[0];
    const float* lat  = (const float*)d_in[1];
    const float* c1   = (const float*)d_in[2];
    const float* c2   = (const float*)d_in[3];
    const float* temp = (const float*)d_in[4];
    const float* u    = (const float*)d_in[5];
    float* out = (float*)d_out;

    char* ws = (char*)d_ws;
    float*          lgP = (float*)ws;                          // 8 MB
    __hip_bfloat16* MTF = (__hip_bfloat16*)(ws + (8 << 20));   // 2 MB, fragment-major

    rl_k1_logits<<<dim3(128, 2, 2), 256, 0, stream>>>(lat, c1, c2, lgP);
    rl_k2_mask  <<<dim3(8, 2, 16), 256, 0, stream>>>(lgP, u, temp, MTF);
    rl_k3_gemm  <<<dim3(16, 16), 1024, 0, stream>>>(x, MTF, out);
}

// Round 16
// 127.038 us; speedup vs baseline: 1.0931x; 1.0931x over previous
//
#include <hip/hip_runtime.h>
#include <hip/hip_bf16.h>

#define FLOAT_EPS 1.1920928955078125e-07f

typedef float f32x4 __attribute__((ext_vector_type(4)));
typedef short s16x8 __attribute__((ext_vector_type(8)));

#define B_ 16
#define P_ 8192
#define I_ 256
#define O_ 128
#define L_ 256
#define IO_ (I_*O_)   // 32768

__device__ __forceinline__ float clip01(float v) {
    return fminf(fmaxf(v, 0.0f), 1.0f);
}
__device__ __forceinline__ f32x4 clip01v(f32x4 v) {
    f32x4 r;
    r[0] = clip01(v[0]); r[1] = clip01(v[1]);
    r[2] = clip01(v[2]); r[3] = clip01(v[3]);
    return r;
}

// ---------------- K1: partial logits, l split 2-way; lat read via scalar loads ------
// grid (128, 2, 2) = (n-block, ks, l-half), block 256.
__global__ __launch_bounds__(256) void rl_k1_logits(
        const float* __restrict__ lat,
        const float* __restrict__ c1, const float* __restrict__ c2,
        float* __restrict__ lgP) {
    const int n  = blockIdx.x * 256 + threadIdx.x;
    const int ks = blockIdx.y;
    const int lh = blockIdx.z;
    const float* __restrict__ C  = (ks ? c2 : c1) + (size_t)lh * 128 * IO_;
    const int lbase = lh * 128;

    float acc[16];
#pragma unroll
    for (int b = 0; b < 16; ++b) acc[b] = 0.0f;

#pragma unroll 4
    for (int l = 0; l < 128; ++l) {
        float cv = C[(size_t)l * IO_ + n];
#pragma unroll
        for (int b = 0; b < 16; ++b)
            acc[b] += lat[b * L_ + lbase + l] * cv;   // uniform -> s_load
    }
    float* o = lgP + ((size_t)(lh * 32 + ks * 16)) * IO_ + n;
#pragma unroll
    for (int b = 0; b < 16; ++b) o[(size_t)b * IO_] = acc[b];
}

// ---------------- K2: double softmax over i, write mask fragment-major bf16 ---------
// grid (8, 2, 16) = (o-tile16, ks, b), block 256 = 16 i-groups x 16 o-lanes.
// Output chunk j = (f*8+kk)*64 + lhi*16 + l15 holds B[f*16+l15][kk*32+lhi*8 .. +7]
// where B[n][i] = mask_s[b][ks][i][o], n = ks*128 + o.
__global__ __launch_bounds__(256) void rl_k2_mask(
        const float* __restrict__ lgP, const float* __restrict__ u,
        const float* __restrict__ temp_p, __hip_bfloat16* __restrict__ MTF) {
    const int oo = threadIdx.x & 15;
    const int g  = threadIdx.x >> 4;     // 16 groups, 16 i's each
    const int o0 = blockIdx.x * 16;
    const int ks = blockIdx.y;
    const int b  = blockIdx.z;

    __shared__ float slab[I_][16];
    __shared__ float red[16][16];

    const float* __restrict__ z0 = lgP + (size_t)(ks * 16 + b) * IO_ + o0 + oo;
    const float* __restrict__ z1 = z0 + (size_t)32 * IO_;
    const float* __restrict__ up = u + ((size_t)b * 2 + ks) * IO_ + o0 + oo;

    float T = temp_p[0];
    T = fminf(fmaxf(T, FLOAT_EPS), 2.0f);
    T = fmaxf(T, 0.001f);
    const float rT = 1.0f / T;

    const int i0 = g * 16, i1 = i0 + 16;

    for (int i = i0; i < i1; ++i)
        slab[i][oo] = z0[(size_t)i * O_] + z1[(size_t)i * O_];
    __syncthreads();

    float m = -INFINITY;
    for (int i = i0; i < i1; ++i) m = fmaxf(m, slab[i][oo]);
    red[g][oo] = m; __syncthreads();
    m = -INFINITY;
#pragma unroll
    for (int j = 0; j < 16; ++j) m = fmaxf(m, red[j][oo]);
    __syncthreads();

    float S = 0.0f;
    for (int i = i0; i < i1; ++i) S += expf(slab[i][oo] - m);
    red[g][oo] = S; __syncthreads();
    S = 0.0f;
#pragma unroll
    for (int j = 0; j < 16; ++j) S += red[j][oo];
    __syncthreads();
    const float invS = 1.0f / S;

    float m2 = -INFINITY;
    for (int i = i0; i < i1; ++i) {
        float p  = expf(slab[i][oo] - m) * invS;
        float uu = fmaxf(up[(size_t)i * O_], FLOAT_EPS);
        float gg = -logf(-logf(uu));
        float s  = (logf(p + FLOAT_EPS) + gg) * rT;
        slab[i][oo] = s;
        m2 = fmaxf(m2, s);
    }
    red[g][oo] = m2; __syncthreads();
    m2 = -INFINITY;
#pragma unroll
    for (int j = 0; j < 16; ++j) m2 = fmaxf(m2, red[j][oo]);
    __syncthreads();

    float S2 = 0.0f;
    for (int i = i0; i < i1; ++i) S2 += expf(slab[i][oo] - m2);
    red[g][oo] = S2; __syncthreads();
    S2 = 0.0f;
#pragma unroll
    for (int j = 0; j < 16; ++j) S2 += red[j][oo];
    const float invS2 = 1.0f / S2;

    // pass 5: write fragment-major. This thread owns n = ks*128+o0+oo (l15 = oo),
    // i = i0..i0+15 -> kk = g>>1, lhi = 2*(g&1) and 2*(g&1)+1.
    const int n  = ks * 128 + o0 + oo;
    const int f  = n >> 4;
    const int j0 = (f * 8 + (g >> 1)) * 64 + (g & 1) * 32 + oo;
    s16x8* __restrict__ MTFb = (s16x8*)MTF + (size_t)b * 8192;

    union { s16x8 v; __hip_bfloat162 h[4]; } c0, c1;
#pragma unroll
    for (int e = 0; e < 8; e += 2) {
        float v0 = expf(slab[i0 + e][oo]     - m2) * invS2;
        float v1 = expf(slab[i0 + e + 1][oo] - m2) * invS2;
        c0.h[e >> 1] = __float22bfloat162_rn(make_float2(v0, v1));
        float w0 = expf(slab[i0 + 8 + e][oo]     - m2) * invS2;
        float w1 = expf(slab[i0 + 8 + e + 1][oo] - m2) * invS2;
        c1.h[e >> 1] = __float22bfloat162_rn(make_float2(w0, w1));
    }
    MTFb[j0]      = c0.v;
    MTFb[j0 + 16] = c1.v;
}

// ---------------- K3: fragment-major LDS B, 16 waves, DENSE concurrent store rows ---
// grid (16, 16) = (512-row slab, b), block 1024 = 16 waves.
// Row remap vs R11: wave w owns rows [w*16, w*16+16) (chunk 0) and [256+w*16, ..)
// (chunk 1), so the 16 in-phase waves' concurrent stores cover 256 CONSECUTIVE rows
// (dense 512 KB window) instead of a strided scatter -> DRAM row-buffer locality.
// B fragments lane-contiguous in LDS: read = base + lane*16 -> zero bank conflicts.
// mfma(A=mask, B=x) -> D[n][p]: lane col (l15) = output row p, regs = 4 consecutive n.
__global__ __launch_bounds__(1024, 4) void rl_k3_gemm(
        const float* __restrict__ X, const __hip_bfloat16* __restrict__ MTF,
        float* __restrict__ OUT) {
    const int tid  = threadIdx.x;
    const int lane = tid & 63, wid = tid >> 6;   // 16 waves
    const int b    = blockIdx.y;

    __shared__ s16x8 BF[8192];   // 128 KB, fragment-major (identity copy of MTF[b])

    const float* __restrict__ Xb    = X + (size_t)b * P_ * I_;
    const s16x8* __restrict__ MTFb  = (const s16x8*)MTF + (size_t)b * 8192;
    float* __restrict__ Ob          = OUT + (size_t)b * P_ * 512;

    const int l15 = lane & 15, lhi = lane >> 4;
    const int rowbase = blockIdx.x * 512 + wid * 16 + l15;   // dense across waves

    // issue x chunk-0 loads first (latency hides under B staging + barrier)
    float4 raw[16];
    {
        const float* s0 = Xb + (size_t)rowbase * I_ + lhi * 8;
#pragma unroll
        for (int kk = 0; kk < 8; ++kk) {
            raw[2 * kk]     = *(const float4*)(s0 + kk * 32);
            raw[2 * kk + 1] = *(const float4*)(s0 + kk * 32 + 4);
        }
    }

    // stage B: identity copy, coalesced global reads, conflict-free LDS writes
#pragma unroll
    for (int it = 0; it < 8; ++it) {
        int j = it * 1024 + tid;
        BF[j] = MTFb[j];
    }
    __syncthreads();

    const float* s1 = Xb + (size_t)(rowbase + 256) * I_ + lhi * 8;

    // ---- chunk 0: compute with chunk-1 prefetch spread through the fn loop ----
    {
        s16x8 af[8];
#pragma unroll
        for (int kk = 0; kk < 8; ++kk) {
            float4 f0 = raw[2 * kk], f1 = raw[2 * kk + 1];
            union { s16x8 v; __hip_bfloat162 h[4]; } cv;
            cv.h[0] = __float22bfloat162_rn(make_float2(f0.x, f0.y));
            cv.h[1] = __float22bfloat162_rn(make_float2(f0.z, f0.w));
            cv.h[2] = __float22bfloat162_rn(make_float2(f1.x, f1.y));
            cv.h[3] = __float22bfloat162_rn(make_float2(f1.z, f1.w));
            af[kk] = cv.v;
        }
        const int prow = rowbase;
        float* __restrict__ oprow = Ob + (size_t)prow * 512 + lhi * 4;

#pragma unroll
        for (int fn = 0; fn < 8; ++fn) {
            // 2 of chunk-1's 16 loads, pinned here -> continuous read issue
            raw[2 * fn]     = *(const float4*)(s1 + fn * 32);
            raw[2 * fn + 1] = *(const float4*)(s1 + fn * 32 + 4);
            __builtin_amdgcn_sched_barrier(0);

            f32x4 acc_a = (f32x4){0.f, 0.f, 0.f, 0.f};
            f32x4 acc_b = (f32x4){0.f, 0.f, 0.f, 0.f};
            const s16x8* pA = BF + (fn * 8) * 64 + lane;
            const s16x8* pB = BF + ((fn + 8) * 8) * 64 + lane;
#pragma unroll
            for (int kk = 0; kk < 8; ++kk) {
                s16x8 bfa = pA[kk * 64];
                s16x8 bfb = pB[kk * 64];
                acc_a = __builtin_amdgcn_mfma_f32_16x16x32_bf16(bfa, af[kk], acc_a, 0, 0, 0);
                acc_b = __builtin_amdgcn_mfma_f32_16x16x32_bf16(bfb, af[kk], acc_b, 0, 0, 0);
            }
            f32x4 s = acc_a + acc_b;
            float* op = oprow + fn * 16;
            __builtin_nontemporal_store(clip01v(s),             (f32x4*)(op));
            __builtin_nontemporal_store(clip01v(s - 1.0f),      (f32x4*)(op + 128));
            __builtin_nontemporal_store(clip01v(acc_a - acc_b), (f32x4*)(op + 256));
            __builtin_nontemporal_store(clip01v(acc_b - acc_a), (f32x4*)(op + 384));
            __builtin_amdgcn_sched_barrier(0);
        }
    }

    // ---- chunk 1: plain compute (no further prefetch) ----
    {
        s16x8 af[8];
#pragma unroll
        for (int kk = 0; kk < 8; ++kk) {
            float4 f0 = raw[2 * kk], f1 = raw[2 * kk + 1];
            union { s16x8 v; __hip_bfloat162 h[4]; } cv;
            cv.h[0] = __float22bfloat162_rn(make_float2(f0.x, f0.y));
            cv.h[1] = __float22bfloat162_rn(make_float2(f0.z, f0.w));
            cv.h[2] = __float22bfloat162_rn(make_float2(f1.x, f1.y));
            cv.h[3] = __float22bfloat162_rn(make_float2(f1.z, f1.w));
            af[kk] = cv.v;
        }
        const int prow = rowbase + 256;
        float* __restrict__ oprow = Ob + (size_t)prow * 512 + lhi * 4;

#pragma unroll
        for (int fn = 0; fn < 8; ++fn) {
            f32x4 acc_a = (f32x4){0.f, 0.f, 0.f, 0.f};
            f32x4 acc_b = (f32x4){0.f, 0.f, 0.f, 0.f};
            const s16x8* pA = BF + (fn * 8) * 64 + lane;
            const s16x8* pB = BF + ((fn + 8) * 8) * 64 + lane;
#pragma unroll
            for (int kk = 0; kk < 8; ++kk) {
                s16x8 bfa = pA[kk * 64];
                s16x8 bfb = pB[kk * 64];
                acc_a = __builtin_amdgcn_mfma_f32_16x16x32_bf16(bfa, af[kk], acc_a, 0, 0, 0);
                acc_b = __builtin_amdgcn_mfma_f32_16x16x32_bf16(bfb, af[kk], acc_b, 0, 0, 0);
            }
            f32x4 s = acc_a + acc_b;
            float* op = oprow + fn * 16;
            __builtin_nontemporal_store(clip01v(s),             (f32x4*)(op));
            __builtin_nontemporal_store(clip01v(s - 1.0f),      (f32x4*)(op + 128));
            __builtin_nontemporal_store(clip01v(acc_a - acc_b), (f32x4*)(op + 256));
            __builtin_nontemporal_store(clip01v(acc_b - acc_a), (f32x4*)(op + 384));
        }
    }
}

extern "C" void kernel_launch(void* const* d_in, const int* in_sizes, int n_in,
                              void* d_out, int out_size, void* d_ws, size_t ws_size,
                              hipStream_t stream) {
    const float* x    = (const float*)d_in[0];
    const float* lat  = (const float*)d_in[1];
    const float* c1   = (const float*)d_in[2];
    const float* c2   = (const float*)d_in[3];
    const float* temp = (const float*)d_in[4];
    const float* u    = (const float*)d_in[5];
    float* out = (float*)d_out;

    char* ws = (char*)d_ws;
    float*          lgP = (float*)ws;                          // 8 MB
    __hip_bfloat16* MTF = (__hip_bfloat16*)(ws + (8 << 20));   // 2 MB, fragment-major

    rl_k1_logits<<<dim3(128, 2, 2), 256, 0, stream>>>(lat, c1, c2, lgP);
    rl_k2_mask  <<<dim3(8, 2, 16), 256, 0, stream>>>(lgP, u, temp, MTF);
    rl_k3_gemm  <<<dim3(16, 16), 1024, 0, stream>>>(x, MTF, out);
}